// Round 1
// baseline (280.301 us; speedup 1.0000x reference)
//
#include <hip/hip_runtime.h>
#include <hip/hip_bf16.h>
#include <cstdint>
#include <cstddef>

typedef __bf16 bf16;
typedef __bf16 bf16x8 __attribute__((ext_vector_type(8)));
typedef __bf16 bf16x4 __attribute__((ext_vector_type(4)));
typedef float f32x4 __attribute__((ext_vector_type(4)));

#define LDS_CAST(p) (__attribute__((address_space(3))) void*)(p)
#define GLB_CAST(p) (const __attribute__((address_space(1))) void*)(p)
#define MFMA16(a, b, c) __builtin_amdgcn_mfma_f32_16x16x32_bf16(a, b, c, 0, 0, 0)

static constexpr int BATCH = 8;
static constexpr int NSEQ  = 1024;
static constexpr int CDIM  = 768;
static constexpr int NH    = 12;
static constexpr int HD    = 64;
static constexpr int MTOT  = BATCH * NSEQ;   // 8192
static constexpr int NC3   = 3 * CDIM;       // 2304

// ---------------- cast fp32 -> bf16 (vectorized) ----------------
__global__ void cast_kernel(const float* __restrict__ src, bf16* __restrict__ dst, int n4) {
    int i = blockIdx.x * blockDim.x + threadIdx.x;
    if (i < n4) {
        float4 v = ((const float4*)src)[i];
        bf16x4 o = { (bf16)v.x, (bf16)v.y, (bf16)v.z, (bf16)v.w };
        ((bf16x4*)dst)[i] = o;
    }
}

// ------------- transpose-cast: dst[n][k] = (bf16)src[k][n] -------------
// coalesced bf16 writes; reads strided but L2-absorbed (small matrices)
__global__ void tcast_kernel(const float* __restrict__ src, bf16* __restrict__ dst,
                             int K, int N) {
    int k = blockIdx.x * blockDim.x + threadIdx.x;
    int n = blockIdx.y;
    if (k < K) dst[(size_t)n * K + k] = (bf16)src[(size_t)k * N + n];
}

// ---------------- GEMM: C[M,Nd] = A[M,K] @ Bt[Nd,K]^T + bias ----------------
// MODE 0: fp32 output (proj). MODE 1: split bf16 q/k -> [B,H,N,D], v -> [B,H,D,N]
template <int MODE>
__global__ __launch_bounds__(256) void gemm_kernel(
    const bf16* __restrict__ A, const bf16* __restrict__ Bt,
    const float* __restrict__ bias, float* __restrict__ outf,
    bf16* __restrict__ q, bf16* __restrict__ kk, bf16* __restrict__ v,
    int Ndim, int K)
{
    __shared__ alignas(16) bf16 sA[128 * 32];
    __shared__ alignas(16) bf16 sB[128 * 32];
    const int tid  = threadIdx.x;
    const int lane = tid & 63;
    const int wid  = tid >> 6;
    const int quad = lane >> 4;
    const int l16  = lane & 15;
    const int wm   = (wid >> 1) * 64;   // wave m-offset in tile
    const int wn   = (wid & 1) * 64;    // wave n-offset in tile
    const int tm   = blockIdx.y * 128;
    const int tn   = blockIdx.x * 128;

    const f32x4 fzero = {0.f, 0.f, 0.f, 0.f};
    f32x4 acc[4][4];
#pragma unroll
    for (int i = 0; i < 4; i++)
#pragma unroll
        for (int j = 0; j < 4; j++) acc[i][j] = fzero;

    // staging: chunk c = tid (rows 0..63) and c = tid+256 (rows 64..127)
    const int srow = tid >> 2;        // 0..63
    const int sk8  = (tid & 3) * 8;   // 0,8,16,24
    const bf16* gA = A  + (size_t)(tm + srow) * K + sk8;
    const bf16* gB = Bt + (size_t)(tn + srow) * K + sk8;
    const size_t rs64 = (size_t)64 * K;
    bf16* dA0 = sA + wid * 512;
    bf16* dA1 = sA + 2048 + wid * 512;
    bf16* dB0 = sB + wid * 512;
    bf16* dB1 = sB + 2048 + wid * 512;

    for (int k0 = 0; k0 < K; k0 += 32) {
        __syncthreads();
        __builtin_amdgcn_global_load_lds(GLB_CAST(gA + k0),        LDS_CAST(dA0), 16, 0, 0);
        __builtin_amdgcn_global_load_lds(GLB_CAST(gA + rs64 + k0), LDS_CAST(dA1), 16, 0, 0);
        __builtin_amdgcn_global_load_lds(GLB_CAST(gB + k0),        LDS_CAST(dB0), 16, 0, 0);
        __builtin_amdgcn_global_load_lds(GLB_CAST(gB + rs64 + k0), LDS_CAST(dB1), 16, 0, 0);
        __syncthreads();

        bf16x8 af[4], bfr[4];
#pragma unroll
        for (int i = 0; i < 4; i++)
            af[i] = *(const bf16x8*)(sA + (wm + i * 16 + l16) * 32 + quad * 8);
#pragma unroll
        for (int i = 0; i < 4; i++)
            bfr[i] = *(const bf16x8*)(sB + (wn + i * 16 + l16) * 32 + quad * 8);
#pragma unroll
        for (int i = 0; i < 4; i++)
#pragma unroll
            for (int j = 0; j < 4; j++) acc[i][j] = MFMA16(af[i], bfr[j], acc[i][j]);
    }

    // epilogue: C/D layout col = l16, row = quad*4 + r  [measured m89]
    if (MODE == 0) {
#pragma unroll
        for (int i = 0; i < 4; i++) {
            int row = tm + wm + i * 16 + quad * 4;
#pragma unroll
            for (int j = 0; j < 4; j++) {
                int col = tn + wn + j * 16 + l16;
                float bv = bias[col];
                float* op = outf + (size_t)row * Ndim + col;
#pragma unroll
                for (int r = 0; r < 4; r++) op[(size_t)r * Ndim] = acc[i][j][r] + bv;
            }
        }
    } else {
#pragma unroll
        for (int i = 0; i < 4; i++) {
            int row = tm + wm + i * 16 + quad * 4;
            int b  = row >> 10;
            int ns = row & 1023;
#pragma unroll
            for (int j = 0; j < 4; j++) {
                int col = tn + wn + j * 16 + l16;
                int t3  = col / 768;
                int rem = col - t3 * 768;
                int h = rem >> 6;
                int d = rem & 63;
                float bv = bias[col];
                if (t3 == 0) {
                    bf16* qp = q + ((size_t)(b * NH + h) * NSEQ + ns) * HD + d;
#pragma unroll
                    for (int r = 0; r < 4; r++) qp[(size_t)r * HD] = (bf16)(acc[i][j][r] + bv);
                } else if (t3 == 1) {
                    bf16* kp = kk + ((size_t)(b * NH + h) * NSEQ + ns) * HD + d;
#pragma unroll
                    for (int r = 0; r < 4; r++) kp[(size_t)r * HD] = (bf16)(acc[i][j][r] + bv);
                } else {
                    // v transposed: [B,H,D,N]; 4 rows (r) are contiguous along N
                    bf16x4 pv = { (bf16)(acc[i][j][0] + bv), (bf16)(acc[i][j][1] + bv),
                                  (bf16)(acc[i][j][2] + bv), (bf16)(acc[i][j][3] + bv) };
                    *(bf16x4*)(v + ((size_t)(b * NH + h) * HD + d) * NSEQ + ns) = pv;
                }
            }
        }
    }
}

// ---------------- flash attention: one block per (b,h,qtile of 64 rows) ----------------
// q,k: [B,H,N,D] bf16; v: [B,H,D,N] bf16; o: [B,N,C] bf16
__global__ __launch_bounds__(256) void attn_kernel(
    const bf16* __restrict__ q, const bf16* __restrict__ k,
    const bf16* __restrict__ v, bf16* __restrict__ o)
{
    __shared__ alignas(16) bf16 sQ[64 * 72];   // row pad +8 -> 2-way bank conflicts only
    __shared__ alignas(16) bf16 sK[64 * 72];
    __shared__ alignas(16) bf16 sVt[64 * 72];  // [d][vrow]
    __shared__ alignas(16) bf16 sP[64 * 72];   // per-wave 16-row slices
    const int tid  = threadIdx.x;
    const int lane = tid & 63;
    const int wid  = tid >> 6;
    const int quad = lane >> 4;
    const int l16  = lane & 15;
    const int qt = blockIdx.x;   // 0..15
    const int bh = blockIdx.y;   // 0..95
    const int b = bh / NH;
    const int h = bh - b * NH;

    const bf16* qb = q + ((size_t)bh * NSEQ + qt * 64) * HD;
    const bf16* kb = k + (size_t)bh * NSEQ * HD;
    const bf16* vb = v + (size_t)bh * HD * NSEQ;

    // stage Q tile (64x64), padded rows
#pragma unroll
    for (int c = 0; c < 2; c++) {
        int ch = tid + c * 256;
        int r = ch >> 3, d8 = (ch & 7) * 8;
        *(bf16x8*)(sQ + r * 72 + d8) = *(const bf16x8*)(qb + r * HD + d8);
    }
    __syncthreads();
    // hoist Q A-fragments (wave owns q-rows wid*16..wid*16+15)
    bf16x8 aq0 = *(const bf16x8*)(sQ + (wid * 16 + l16) * 72 + quad * 8);
    bf16x8 aq1 = *(const bf16x8*)(sQ + (wid * 16 + l16) * 72 + 32 + quad * 8);

    const f32x4 fzero = {0.f, 0.f, 0.f, 0.f};
    f32x4 oacc[4];
#pragma unroll
    for (int di = 0; di < 4; di++) oacc[di] = fzero;
    float m_run[4], l_run[4];
#pragma unroll
    for (int r = 0; r < 4; r++) { m_run[r] = -1e30f; l_run[r] = 0.f; }
    const float scale = 0.125f;  // 1/sqrt(64)

    for (int kt = 0; kt < 16; kt++) {
        __syncthreads();  // previous iter's LDS reads done
#pragma unroll
        for (int c = 0; c < 2; c++) {
            int ch = tid + c * 256;
            int r = ch >> 3, d8 = (ch & 7) * 8;
            *(bf16x8*)(sK  + r * 72 + d8) = *(const bf16x8*)(kb + ((size_t)(kt * 64 + r)) * HD + d8);
            *(bf16x8*)(sVt + r * 72 + d8) = *(const bf16x8*)(vb + (size_t)r * NSEQ + kt * 64 + d8);
        }
        __syncthreads();

        // S = Q K^T (wave's 16 rows x 64 cols)
        f32x4 s[4];
#pragma unroll
        for (int ni = 0; ni < 4; ni++) s[ni] = fzero;
#pragma unroll
        for (int ni = 0; ni < 4; ni++) {
            bf16x8 bk0 = *(const bf16x8*)(sK + (ni * 16 + l16) * 72 + quad * 8);
            bf16x8 bk1 = *(const bf16x8*)(sK + (ni * 16 + l16) * 72 + 32 + quad * 8);
            s[ni] = MFMA16(aq0, bk0, s[ni]);
            s[ni] = MFMA16(aq1, bk1, s[ni]);
        }
#pragma unroll
        for (int ni = 0; ni < 4; ni++) s[ni] *= scale;

        // online softmax: row = quad*4 + r, spread over 16 lanes of the quad group
        float mnew[4], alpha[4], rs[4];
#pragma unroll
        for (int r = 0; r < 4; r++) {
            float mx = fmaxf(fmaxf(s[0][r], s[1][r]), fmaxf(s[2][r], s[3][r]));
#pragma unroll
            for (int off = 1; off < 16; off <<= 1) mx = fmaxf(mx, __shfl_xor(mx, off, 64));
            mnew[r] = fmaxf(m_run[r], mx);
            alpha[r] = __expf(m_run[r] - mnew[r]);
            m_run[r] = mnew[r];
            rs[r] = 0.f;
        }
#pragma unroll
        for (int ni = 0; ni < 4; ni++)
#pragma unroll
            for (int r = 0; r < 4; r++) {
                float p = __expf(s[ni][r] - mnew[r]);
                s[ni][r] = p;
                rs[r] += p;
            }
#pragma unroll
        for (int r = 0; r < 4; r++) {
#pragma unroll
            for (int off = 1; off < 16; off <<= 1) rs[r] += __shfl_xor(rs[r], off, 64);
            l_run[r] = l_run[r] * alpha[r] + rs[r];
        }
#pragma unroll
        for (int di = 0; di < 4; di++)
#pragma unroll
            for (int r = 0; r < 4; r++) oacc[di][r] *= alpha[r];

        // P: C-layout -> LDS (wave-private 16x64 slice, padded) -> A-layout
#pragma unroll
        for (int ni = 0; ni < 4; ni++)
#pragma unroll
            for (int r = 0; r < 4; r++)
                sP[(wid * 16 + quad * 4 + r) * 72 + ni * 16 + l16] = (bf16)s[ni][r];

        // O += P @ V
#pragma unroll
        for (int ks = 0; ks < 2; ks++) {
            bf16x8 ap = *(const bf16x8*)(sP + (wid * 16 + l16) * 72 + ks * 32 + quad * 8);
#pragma unroll
            for (int di = 0; di < 4; di++) {
                bf16x8 bv = *(const bf16x8*)(sVt + (di * 16 + l16) * 72 + ks * 32 + quad * 8);
                oacc[di] = MFMA16(ap, bv, oacc[di]);
            }
        }
    }

    float inv[4];
#pragma unroll
    for (int r = 0; r < 4; r++) inv[r] = 1.f / l_run[r];
    bf16* ob = o + ((size_t)b * NSEQ + qt * 64 + wid * 16) * CDIM + h * HD;
#pragma unroll
    for (int di = 0; di < 4; di++)
#pragma unroll
        for (int r = 0; r < 4; r++)
            ob[(size_t)(quad * 4 + r) * CDIM + di * 16 + l16] = (bf16)(oacc[di][r] * inv[r]);
}

// ---------------------------------------------------------------
extern "C" void kernel_launch(void* const* d_in, const int* in_sizes, int n_in,
                              void* d_out, int out_size, void* d_ws, size_t ws_size,
                              hipStream_t stream)
{
    const float* x     = (const float*)d_in[0];
    const float* Wqkv  = (const float*)d_in[1];
    const float* bqkv  = (const float*)d_in[2];
    const float* Wproj = (const float*)d_in[3];
    const float* bproj = (const float*)d_in[4];
    float* out = (float*)d_out;

    char* ws = (char*)d_ws;
    const size_t MC2 = (size_t)MTOT * CDIM * 2;
    bf16* xb     = (bf16*)ws; ws += MC2;                      // x cast        [8192,768]
    bf16* wqkvt  = (bf16*)ws; ws += (size_t)NC3 * CDIM * 2;   // Wqkv^T        [2304,768]
    bf16* wprojt = (bf16*)ws; ws += (size_t)CDIM * CDIM * 2;  // Wproj^T       [768,768]
    bf16* qw     = (bf16*)ws; ws += MC2;                      // q  [B,H,N,D]
    bf16* kw     = (bf16*)ws; ws += MC2;                      // k  [B,H,N,D]
    bf16* vw     = (bf16*)ws; ws += MC2;                      // v  [B,H,D,N]
    bf16* ow     = (bf16*)ws; ws += MC2;                      // attn out [B,N,C]

    int n4 = MTOT * CDIM / 4;
    cast_kernel<<<dim3((n4 + 255) / 256), dim3(256), 0, stream>>>(x, xb, n4);
    tcast_kernel<<<dim3(3, NC3),  dim3(256), 0, stream>>>(Wqkv,  wqkvt,  CDIM, NC3);
    tcast_kernel<<<dim3(3, CDIM), dim3(256), 0, stream>>>(Wproj, wprojt, CDIM, CDIM);

    gemm_kernel<1><<<dim3(NC3 / 128, MTOT / 128), dim3(256), 0, stream>>>(
        xb, wqkvt, bqkv, nullptr, qw, kw, vw, NC3, CDIM);

    attn_kernel<<<dim3(NSEQ / 64, BATCH * NH), dim3(256), 0, stream>>>(qw, kw, vw, ow);

    gemm_kernel<0><<<dim3(CDIM / 128, MTOT / 128), dim3(256), 0, stream>>>(
        ow, wprojt, bproj, out, nullptr, nullptr, nullptr, CDIM, CDIM);
}

// Round 2
// 227.520 us; speedup vs baseline: 1.2320x; 1.2320x over previous
//
#include <hip/hip_runtime.h>
#include <hip/hip_bf16.h>
#include <cstdint>
#include <cstddef>

typedef __bf16 bf16;
typedef __bf16 bf16x8 __attribute__((ext_vector_type(8)));
typedef __bf16 bf16x4 __attribute__((ext_vector_type(4)));
typedef __bf16 bf16x2 __attribute__((ext_vector_type(2)));
typedef float f32x4 __attribute__((ext_vector_type(4)));
typedef float f32x16 __attribute__((ext_vector_type(16)));
typedef unsigned int u32;
typedef u32 u32x4 __attribute__((ext_vector_type(4)));

#define LDS_CAST(p) (__attribute__((address_space(3))) void*)(p)
#define GLB_CAST(p) (const __attribute__((address_space(1))) void*)(p)
#define MFMA16(a, b, c) __builtin_amdgcn_mfma_f32_16x16x32_bf16(a, b, c, 0, 0, 0)
#define MFMA32(a, b, c) __builtin_amdgcn_mfma_f32_32x32x16_bf16(a, b, c, 0, 0, 0)

// exp in log2 domain when the raw exp2 builtin exists: fold scale*log2(e) into Q.
#if __has_builtin(__builtin_amdgcn_exp2f)
#define EXPF(x) __builtin_amdgcn_exp2f(x)
#define QK_SCALE 0.18033688011112042f  /* 0.125 * log2(e) */
#else
#define EXPF(x) __expf(x)
#define QK_SCALE 0.125f
#endif

static constexpr int BATCH = 8;
static constexpr int NSEQ  = 1024;
static constexpr int CDIM  = 768;
static constexpr int NH    = 12;
static constexpr int HD    = 64;
static constexpr int MTOT  = BATCH * NSEQ;   // 8192
static constexpr int NC3   = 3 * CDIM;       // 2304

__device__ inline u32 pkbf(float a, float b) {
    bf16x2 t = { (bf16)a, (bf16)b };
    return __builtin_bit_cast(u32, t);
}

// ---------------- cast fp32 -> bf16 (vectorized) ----------------
__global__ void cast_kernel(const float* __restrict__ src, bf16* __restrict__ dst, int n4) {
    int i = blockIdx.x * blockDim.x + threadIdx.x;
    if (i < n4) {
        float4 v = ((const float4*)src)[i];
        bf16x4 o = { (bf16)v.x, (bf16)v.y, (bf16)v.z, (bf16)v.w };
        ((bf16x4*)dst)[i] = o;
    }
}

// ------------- transpose-cast: dst[n][k] = (bf16)src[k][n] -------------
__global__ void tcast_kernel(const float* __restrict__ src, bf16* __restrict__ dst,
                             int K, int N) {
    int k = blockIdx.x * blockDim.x + threadIdx.x;
    int n = blockIdx.y;
    if (k < K) dst[(size_t)n * K + k] = (bf16)src[(size_t)k * N + n];
}

// ---------------- GEMM: C[M,Nd] = A[M,K] @ Bt[Nd,K]^T + bias ----------------
// MODE 0: fp32 output (proj). MODE 1: split bf16 q/k -> [B,H,N,D] (q pre-scaled), v -> [B,H,D,N]
template <int MODE>
__global__ __launch_bounds__(256) void gemm_kernel(
    const bf16* __restrict__ A, const bf16* __restrict__ Bt,
    const float* __restrict__ bias, float* __restrict__ outf,
    bf16* __restrict__ q, bf16* __restrict__ kk, bf16* __restrict__ v,
    int Ndim, int K)
{
    __shared__ alignas(16) bf16 sA[128 * 32];
    __shared__ alignas(16) bf16 sB[128 * 32];
    const int tid  = threadIdx.x;
    const int lane = tid & 63;
    const int wid  = tid >> 6;
    const int quad = lane >> 4;
    const int l16  = lane & 15;
    const int wm   = (wid >> 1) * 64;
    const int wn   = (wid & 1) * 64;
    const int tm   = blockIdx.y * 128;
    const int tn   = blockIdx.x * 128;

    const f32x4 fzero = {0.f, 0.f, 0.f, 0.f};
    f32x4 acc[4][4];
#pragma unroll
    for (int i = 0; i < 4; i++)
#pragma unroll
        for (int j = 0; j < 4; j++) acc[i][j] = fzero;

    const int srow = tid >> 2;
    const int sk8  = (tid & 3) * 8;
    const bf16* gA = A  + (size_t)(tm + srow) * K + sk8;
    const bf16* gB = Bt + (size_t)(tn + srow) * K + sk8;
    const size_t rs64 = (size_t)64 * K;
    bf16* dA0 = sA + wid * 512;
    bf16* dA1 = sA + 2048 + wid * 512;
    bf16* dB0 = sB + wid * 512;
    bf16* dB1 = sB + 2048 + wid * 512;

    for (int k0 = 0; k0 < K; k0 += 32) {
        __syncthreads();
        __builtin_amdgcn_global_load_lds(GLB_CAST(gA + k0),        LDS_CAST(dA0), 16, 0, 0);
        __builtin_amdgcn_global_load_lds(GLB_CAST(gA + rs64 + k0), LDS_CAST(dA1), 16, 0, 0);
        __builtin_amdgcn_global_load_lds(GLB_CAST(gB + k0),        LDS_CAST(dB0), 16, 0, 0);
        __builtin_amdgcn_global_load_lds(GLB_CAST(gB + rs64 + k0), LDS_CAST(dB1), 16, 0, 0);
        __syncthreads();

        bf16x8 af[4], bfr[4];
#pragma unroll
        for (int i = 0; i < 4; i++)
            af[i] = *(const bf16x8*)(sA + (wm + i * 16 + l16) * 32 + quad * 8);
#pragma unroll
        for (int i = 0; i < 4; i++)
            bfr[i] = *(const bf16x8*)(sB + (wn + i * 16 + l16) * 32 + quad * 8);
#pragma unroll
        for (int i = 0; i < 4; i++)
#pragma unroll
            for (int j = 0; j < 4; j++) acc[i][j] = MFMA16(af[i], bfr[j], acc[i][j]);
    }

    if (MODE == 0) {
#pragma unroll
        for (int i = 0; i < 4; i++) {
            int row = tm + wm + i * 16 + quad * 4;
#pragma unroll
            for (int j = 0; j < 4; j++) {
                int col = tn + wn + j * 16 + l16;
                float bv = bias[col];
                float* op = outf + (size_t)row * Ndim + col;
#pragma unroll
                for (int r = 0; r < 4; r++) op[(size_t)r * Ndim] = acc[i][j][r] + bv;
            }
        }
    } else {
#pragma unroll
        for (int i = 0; i < 4; i++) {
            int row = tm + wm + i * 16 + quad * 4;
            int b  = row >> 10;
            int ns = row & 1023;
#pragma unroll
            for (int j = 0; j < 4; j++) {
                int col = tn + wn + j * 16 + l16;
                int t3  = col / 768;
                int rem = col - t3 * 768;
                int h = rem >> 6;
                int d = rem & 63;
                float bv = bias[col];
                if (t3 == 0) {
                    bf16* qp = q + ((size_t)(b * NH + h) * NSEQ + ns) * HD + d;
#pragma unroll
                    for (int r = 0; r < 4; r++)
                        qp[(size_t)r * HD] = (bf16)((acc[i][j][r] + bv) * (float)QK_SCALE);
                } else if (t3 == 1) {
                    bf16* kp = kk + ((size_t)(b * NH + h) * NSEQ + ns) * HD + d;
#pragma unroll
                    for (int r = 0; r < 4; r++) kp[(size_t)r * HD] = (bf16)(acc[i][j][r] + bv);
                } else {
                    bf16x4 pv = { (bf16)(acc[i][j][0] + bv), (bf16)(acc[i][j][1] + bv),
                                  (bf16)(acc[i][j][2] + bv), (bf16)(acc[i][j][3] + bv) };
                    *(bf16x4*)(v + ((size_t)(b * NH + h) * HD + d) * NSEQ + ns) = pv;
                }
            }
        }
    }
}

// ---------------- flash attention v2: S^T/O^T formulation, 32x32 MFMA ----------------
// q (pre-scaled): [B,H,N,D]; k: [B,H,N,D]; v: [B,H,D,N]; o: [B,N,C] bf16
// block: 256 thr (4 waves), Q-tile 128 (wave w owns q-quarter w*32.. via lane&31), kv-tile 64.
// LDS staged via global_load_lds(16B) with XOR-swizzle: slot (r,cs) holds global chunk (r, cs^(r&7)).
__global__ __launch_bounds__(256) void attn_kernel(
    const bf16* __restrict__ q, const bf16* __restrict__ k,
    const bf16* __restrict__ v, bf16* __restrict__ o)
{
    __shared__ alignas(16) bf16 sQ[128 * 64];
    __shared__ alignas(16) bf16 sK[2][64 * 64];
    __shared__ alignas(16) bf16 sV[2][64 * 64];
    const int tid  = threadIdx.x;
    const int lane = tid & 63;
    const int w    = tid >> 6;
    const int h    = lane >> 5;    // half-of-wave index
    const int l32  = lane & 31;
    const int qt = blockIdx.x;     // 0..7
    const int bh = blockIdx.y;     // 0..95
    const int b = bh / NH, hh = bh - b * NH;

    const bf16* qb = q + ((size_t)bh * NSEQ + qt * 128) * HD;
    const bf16* kb = k + (size_t)bh * NSEQ * HD;
    const bf16* vb = v + (size_t)bh * HD * NSEQ;

    // ---- stage Q (128x64 = 1024 slots of 16B) + first K/V tile
#pragma unroll
    for (int i = 0; i < 4; i++) {
        int slot = w * 256 + i * 64 + lane;
        int r = slot >> 3, cs = slot & 7;
        __builtin_amdgcn_global_load_lds(GLB_CAST(qb + r * HD + ((cs ^ (r & 7)) * 8)),
                                         LDS_CAST(sQ + (w * 256 + i * 64) * 8), 16, 0, 0);
    }
    auto stageKV = [&](int kt, int buf) {
#pragma unroll
        for (int i = 0; i < 2; i++) {
            int slot = w * 128 + i * 64 + lane;
            int r = slot >> 3, cs = slot & 7;
            int cc = (cs ^ (r & 7)) * 8;
            __builtin_amdgcn_global_load_lds(GLB_CAST(kb + (size_t)(kt * 64 + r) * HD + cc),
                                             LDS_CAST(&sK[buf][(w * 128 + i * 64) * 8]), 16, 0, 0);
            __builtin_amdgcn_global_load_lds(GLB_CAST(vb + (size_t)r * NSEQ + kt * 64 + cc),
                                             LDS_CAST(&sV[buf][(w * 128 + i * 64) * 8]), 16, 0, 0);
        }
    };
    stageKV(0, 0);
    __syncthreads();   // drains Q + buf0

    // hoist Q fragments (B-operand: n = q = l32, k = d)
    bf16x8 qf[4];
    {
        int row = w * 32 + l32, rx = row & 7;
#pragma unroll
        for (int cd = 0; cd < 4; cd++)
            qf[cd] = *(const bf16x8*)(sQ + (row * 8 + ((2 * cd + h) ^ rx)) * 8);
    }

    f32x16 accO[2];
#pragma unroll
    for (int dt = 0; dt < 2; dt++)
#pragma unroll
        for (int i = 0; i < 16; i++) accO[dt][i] = 0.f;
    float m_run = -3e38f, l_run = 0.f;

    for (int kt = 0; kt < 16; kt++) {
        const int cur = kt & 1;
        __syncthreads();                    // prev iter's reads done; cur buf loads drained
        if (kt < 15) stageKV(kt + 1, 1 - cur);  // prefetch overlaps compute below
        const bf16* sKc = sK[cur];
        const bf16* sVc = sV[cur];

        // ---- S^T = K · Q^T : D col = q (l32), row = kv_local
        f32x16 accS[2];
#pragma unroll
        for (int kvt = 0; kvt < 2; kvt++)
#pragma unroll
            for (int i = 0; i < 16; i++) accS[kvt][i] = 0.f;
#pragma unroll
        for (int kvt = 0; kvt < 2; kvt++) {
            int row = kvt * 32 + l32, rx = row & 7;
#pragma unroll
            for (int cd = 0; cd < 4; cd++) {
                bf16x8 kf = *(const bf16x8*)(sKc + (row * 8 + ((2 * cd + h) ^ rx)) * 8);
                accS[kvt] = MFMA32(kf, qf[cd], accS[kvt]);
            }
        }

        // ---- online softmax along kv (lane holds 32 of 64 kv values for its q)
        float tmv[16];
#pragma unroll
        for (int i = 0; i < 16; i++) tmv[i] = fmaxf(accS[0][i], accS[1][i]);
#pragma unroll
        for (int s = 8; s >= 1; s >>= 1)
#pragma unroll
            for (int i = 0; i < s; i++) tmv[i] = fmaxf(tmv[i], tmv[i + s]);
        float tmax = fmaxf(tmv[0], __shfl_xor(tmv[0], 32));
        float mnew = fmaxf(m_run, tmax);
        float alpha = EXPF(m_run - mnew);
        m_run = mnew;

        float tsv[16];
#pragma unroll
        for (int kvt = 0; kvt < 2; kvt++)
#pragma unroll
            for (int i = 0; i < 16; i++) {
                float p = EXPF(accS[kvt][i] - mnew);
                accS[kvt][i] = p;
            }
#pragma unroll
        for (int i = 0; i < 16; i++) tsv[i] = accS[0][i] + accS[1][i];
#pragma unroll
        for (int s = 8; s >= 1; s >>= 1)
#pragma unroll
            for (int i = 0; i < s; i++) tsv[i] += tsv[i + s];
        float rs = tsv[0] + __shfl_xor(tsv[0], 32);
        l_run = l_run * alpha + rs;
#pragma unroll
        for (int dt = 0; dt < 2; dt++)
#pragma unroll
            for (int i = 0; i < 16; i++) accO[dt][i] *= alpha;

        // ---- P: S^T C-layout -> PV B-operand, register-only (exchange with lane^32)
        u32 pr[2][4][2];
#pragma unroll
        for (int kvt = 0; kvt < 2; kvt++)
#pragma unroll
            for (int g = 0; g < 4; g++) {
                pr[kvt][g][0] = pkbf(accS[kvt][4 * g + 0], accS[kvt][4 * g + 1]);
                pr[kvt][g][1] = pkbf(accS[kvt][4 * g + 2], accS[kvt][4 * g + 3]);
            }
        bf16x8 pf[4];
#pragma unroll
        for (int c = 0; c < 4; c++) {
            int kvt = c >> 1, c1 = c & 1;
            u32 u00 = pr[kvt][2 * c1][0],     u01 = pr[kvt][2 * c1][1];
            u32 u10 = pr[kvt][2 * c1 + 1][0], u11 = pr[kvt][2 * c1 + 1][1];
            u32 y0 = h ? u10 : u00, y1 = h ? u11 : u01;   // regs indexed by own h (own j-half)
            u32 z0 = h ? u00 : u10, z1 = h ? u01 : u11;   // regs the partner needs from me
            u32 w0 = (u32)__shfl_xor((int)z0, 32);
            u32 w1 = (u32)__shfl_xor((int)z1, 32);
            u32x4 fv = { h ? w0 : y0, h ? w1 : y1, h ? y0 : w0, h ? y1 : w1 };
            pf[c] = __builtin_bit_cast(bf16x8, fv);
        }

        // ---- O^T += V^T · P^T : D col = q (l32), row = d_local
#pragma unroll
        for (int dt = 0; dt < 2; dt++) {
            int row = dt * 32 + l32, rx = row & 7;
#pragma unroll
            for (int c = 0; c < 4; c++) {
                bf16x8 vf = *(const bf16x8*)(sVc + (row * 8 + ((2 * c + h) ^ rx)) * 8);
                accO[dt] = MFMA32(vf, pf[c], accO[dt]);
            }
        }
    }

    // ---- epilogue: d_local = (r&3) + 8*(r>>2) + 4*h
    float inv = 1.f / l_run;
    bf16* ob = o + ((size_t)b * NSEQ + qt * 128 + w * 32 + l32) * CDIM + hh * HD;
#pragma unroll
    for (int dt = 0; dt < 2; dt++)
#pragma unroll
        for (int g = 0; g < 4; g++) {
            bf16x4 t = { (bf16)(accO[dt][4 * g + 0] * inv), (bf16)(accO[dt][4 * g + 1] * inv),
                         (bf16)(accO[dt][4 * g + 2] * inv), (bf16)(accO[dt][4 * g + 3] * inv) };
            *(bf16x4*)(ob + dt * 32 + 8 * g + 4 * h) = t;
        }
}

// ---------------------------------------------------------------
extern "C" void kernel_launch(void* const* d_in, const int* in_sizes, int n_in,
                              void* d_out, int out_size, void* d_ws, size_t ws_size,
                              hipStream_t stream)
{
    const float* x     = (const float*)d_in[0];
    const float* Wqkv  = (const float*)d_in[1];
    const float* bqkv  = (const float*)d_in[2];
    const float* Wproj = (const float*)d_in[3];
    const float* bproj = (const float*)d_in[4];
    float* out = (float*)d_out;

    char* ws = (char*)d_ws;
    const size_t MC2 = (size_t)MTOT * CDIM * 2;
    bf16* xb     = (bf16*)ws; ws += MC2;
    bf16* wqkvt  = (bf16*)ws; ws += (size_t)NC3 * CDIM * 2;
    bf16* wprojt = (bf16*)ws; ws += (size_t)CDIM * CDIM * 2;
    bf16* qw     = (bf16*)ws; ws += MC2;
    bf16* kw     = (bf16*)ws; ws += MC2;
    bf16* vw     = (bf16*)ws; ws += MC2;
    bf16* ow     = (bf16*)ws; ws += MC2;

    int n4 = MTOT * CDIM / 4;
    cast_kernel<<<dim3((n4 + 255) / 256), dim3(256), 0, stream>>>(x, xb, n4);
    tcast_kernel<<<dim3(3, NC3),  dim3(256), 0, stream>>>(Wqkv,  wqkvt,  CDIM, NC3);
    tcast_kernel<<<dim3(3, CDIM), dim3(256), 0, stream>>>(Wproj, wprojt, CDIM, CDIM);

    gemm_kernel<1><<<dim3(NC3 / 128, MTOT / 128), dim3(256), 0, stream>>>(
        xb, wqkvt, bqkv, nullptr, qw, kw, vw, NC3, CDIM);

    attn_kernel<<<dim3(NSEQ / 128, BATCH * NH), dim3(256), 0, stream>>>(qw, kw, vw, ow);

    gemm_kernel<0><<<dim3(CDIM / 128, MTOT / 128), dim3(256), 0, stream>>>(
        ow, wprojt, bproj, out, nullptr, nullptr, nullptr, CDIM, CDIM);
}